// Round 1
// baseline (2088.676 us; speedup 1.0000x reference)
//
#include <hip/hip_runtime.h>
#include <cmath>

#define S_TOK 8192
#define MDIM  2048
#define NEXP  8
#define HDIM  8192
#define CCAP  2048

typedef unsigned short u16;
typedef __attribute__((ext_vector_type(8))) short short8;
typedef __attribute__((ext_vector_type(4))) float f32x4;

// ---- fp32 -> bf16 round-to-nearest-even ----
__device__ __forceinline__ u16 f2bf(float f) {
  unsigned u = __float_as_uint(f);
  unsigned r = (u + 0x7fffu + ((u >> 16) & 1u)) >> 16;
  return (u16)r;
}

// ---- async global -> LDS, 16B per lane (global_load_lds_dwordx4) ----
__device__ __forceinline__ void async16(const u16* g, u16* l) {
  __builtin_amdgcn_global_load_lds(
      (__attribute__((address_space(1))) void*)(u16*)g,
      (__attribute__((address_space(3))) void*)l, 16, 0, 0);
}

// ================= gate: logits in double, argmax + softmax weight ==========
__global__ __launch_bounds__(256) void gate_kernel(const float* __restrict__ x,
                                                   const float* __restrict__ Wg,
                                                   int* __restrict__ eidx,
                                                   float* __restrict__ gatew) {
  int s = blockIdx.x * 4 + (threadIdx.x >> 6);  // one wave per token
  int lane = threadIdx.x & 63;
  const float* xr = x + (size_t)s * MDIM;
  double acc[NEXP];
#pragma unroll
  for (int e = 0; e < NEXP; e++) acc[e] = 0.0;
  for (int j = lane; j < MDIM; j += 64) {
    float xv = xr[j];
    const float4* w4 = (const float4*)(Wg + (size_t)j * NEXP);
    float4 w0 = w4[0], w1 = w4[1];
    acc[0] += (double)xv * (double)w0.x; acc[1] += (double)xv * (double)w0.y;
    acc[2] += (double)xv * (double)w0.z; acc[3] += (double)xv * (double)w0.w;
    acc[4] += (double)xv * (double)w1.x; acc[5] += (double)xv * (double)w1.y;
    acc[6] += (double)xv * (double)w1.z; acc[7] += (double)xv * (double)w1.w;
  }
#pragma unroll
  for (int e = 0; e < NEXP; e++) {
#pragma unroll
    for (int off = 32; off > 0; off >>= 1) acc[e] += __shfl_xor(acc[e], off);
  }
  if (lane == 0) {
    double m = acc[0]; int best = 0;
#pragma unroll
    for (int e = 1; e < NEXP; e++) if (acc[e] > m) { m = acc[e]; best = e; }
    double ssum = 0.0;
#pragma unroll
    for (int e = 0; e < NEXP; e++) ssum += exp(acc[e] - m);
    eidx[s] = best;
    gatew[s] = (float)(1.0 / ssum);
  }
}

// ============ ordered per-expert cumsum (capacity), inverse map =============
__global__ __launch_bounds__(256) void scan_kernel(const int* __restrict__ eidx,
                                                   float* __restrict__ gatew,
                                                   int* __restrict__ slot,
                                                   int* __restrict__ toks,
                                                   int* __restrict__ counts) {
  __shared__ int cnt[256][NEXP];
  int t = threadIdx.x;
  int loc[NEXP];
#pragma unroll
  for (int e = 0; e < NEXP; e++) loc[e] = 0;
  int base = t * 32;
  for (int i = 0; i < 32; i++) loc[eidx[base + i]]++;
#pragma unroll
  for (int e = 0; e < NEXP; e++) cnt[t][e] = loc[e];
  __syncthreads();
  if (t < NEXP) {
    int run = 0;
    for (int i = 0; i < 256; i++) { int v = cnt[i][t]; cnt[i][t] = run; run += v; }
    counts[t] = run < CCAP ? run : CCAP;
  }
  __syncthreads();
  int off[NEXP];
#pragma unroll
  for (int e = 0; e < NEXP; e++) off[e] = cnt[t][e];
  for (int i = 0; i < 32; i++) {
    int s = base + i;
    int e = eidx[s];
    int p = off[e]++;
    if (p < CCAP) { slot[s] = p; toks[e * CCAP + p] = s; }
    else          { slot[s] = -1; gatew[s] = 0.f; }
  }
}

// ======== dispatch: gather x row -> bf16 -> xd[e*C + slot] ==================
__global__ __launch_bounds__(256) void scatter_kernel(const float* __restrict__ x,
                                                      const int* __restrict__ eidx,
                                                      const int* __restrict__ slot,
                                                      u16* __restrict__ xd) {
  int s = blockIdx.x;
  int sl = slot[s];
  if (sl < 0) return;
  int e = eidx[s];
  int t = threadIdx.x;
  const float4* src = (const float4*)(x + (size_t)s * MDIM);
  uint4* dst = (uint4*)(xd + ((size_t)e * CCAP + sl) * MDIM);
  float4 v0 = src[t * 2], v1 = src[t * 2 + 1];
  union { u16 h[8]; uint4 v; } u;
  u.h[0] = f2bf(v0.x); u.h[1] = f2bf(v0.y); u.h[2] = f2bf(v0.z); u.h[3] = f2bf(v0.w);
  u.h[4] = f2bf(v1.x); u.h[5] = f2bf(v1.y); u.h[6] = f2bf(v1.z); u.h[7] = f2bf(v1.w);
  dst[t] = u.v;
}

// ===== weight fp32 [E][R][Cc]  ->  bf16 [E][Cc][R] (B^T layout for GEMM) ====
__global__ __launch_bounds__(256) void transpose_convert(const float* __restrict__ src,
                                                         u16* __restrict__ dst,
                                                         int R, int Cc) {
  __shared__ float t[32][33];
  int e = blockIdx.z;
  int c0 = blockIdx.x * 32, r0 = blockIdx.y * 32;
  int tx = threadIdx.x, ty = threadIdx.y;  // 32 x 8
  const float* s = src + (size_t)e * R * Cc;
  u16* d = dst + (size_t)e * R * Cc;
#pragma unroll
  for (int i = 0; i < 4; i++) t[ty + 8 * i][tx] = s[(size_t)(r0 + ty + 8 * i) * Cc + c0 + tx];
  __syncthreads();
#pragma unroll
  for (int i = 0; i < 4; i++)
    d[(size_t)(c0 + ty + 8 * i) * R + r0 + tx] = f2bf(t[tx][ty + 8 * i]);
}

// ============ grouped expert GEMM, m97 structure, fused epilogues ===========
// A: [E][CCAP][K] bf16 row-major. B: [E][N][K] bf16 (B^T). EPI 0: Out = gelu -> h bf16.
// EPI 1: Out = d_out f32, scattered by toks, scaled by gatew.
template <int K, int EPI>
__global__ __launch_bounds__(256) void moe_gemm(const u16* __restrict__ A,
                                                const u16* __restrict__ B,
                                                void* __restrict__ OutP,
                                                const int* __restrict__ counts,
                                                const int* __restrict__ toks,
                                                const float* __restrict__ gatew,
                                                int N) {
  int e = blockIdx.z;
  int cnt = counts[e];
  int row0 = blockIdx.y * 128;
  if (row0 >= cnt) return;  // skip empty capacity tiles
  int n0 = blockIdx.x * 128;

  __shared__ __align__(16) u16 sA[128 * 32];
  __shared__ __align__(16) u16 sB[128 * 32];

  const u16* Ab = A + (size_t)e * CCAP * K + (size_t)row0 * K;
  const u16* Bb = B + (size_t)e * N * K + (size_t)n0 * K;

  int tid = threadIdx.x;
  int lane = tid & 63, wave = tid >> 6;
  int rS = tid >> 2;          // staging row 0..63
  int kS = (tid & 3) * 8;     // staging k elem offset (16B chunks)
  int wm = (wave & 1) * 64, wn = (wave >> 1) * 64;
  int fr = lane & 15;         // fragment row (m or n)
  int fk = (lane >> 4) * 8;   // fragment k offset

  f32x4 acc[4][4];
#pragma unroll
  for (int i = 0; i < 4; i++)
#pragma unroll
    for (int j = 0; j < 4; j++) acc[i][j] = (f32x4)0.f;

  for (int kk = 0; kk < K; kk += 32) {
#pragma unroll
    for (int i = 0; i < 2; i++) {
      int r = i * 64 + rS;
      async16(Ab + (size_t)r * K + kk + kS, &sA[r * 32 + kS]);
      async16(Bb + (size_t)r * K + kk + kS, &sB[r * 32 + kS]);
    }
    __syncthreads();  // drains vmcnt -> tiles visible
    short8 a[4], b[4];
#pragma unroll
    for (int mt = 0; mt < 4; mt++) a[mt] = *(const short8*)&sA[(wm + mt * 16 + fr) * 32 + fk];
#pragma unroll
    for (int nt = 0; nt < 4; nt++) b[nt] = *(const short8*)&sB[(wn + nt * 16 + fr) * 32 + fk];
#pragma unroll
    for (int mt = 0; mt < 4; mt++)
#pragma unroll
      for (int nt = 0; nt < 4; nt++)
        acc[mt][nt] = __builtin_amdgcn_mfma_f32_16x16x32_bf16(a[mt], b[nt], acc[mt][nt], 0, 0, 0);
    __syncthreads();  // all reads done before next overwrite
  }

  if constexpr (EPI == 0) {
    u16* hout = (u16*)OutP + (size_t)e * CCAP * N;
#pragma unroll
    for (int mt = 0; mt < 4; mt++) {
      int rbase = row0 + wm + mt * 16 + (lane >> 4) * 4;
#pragma unroll
      for (int nt = 0; nt < 4; nt++) {
        int col = n0 + wn + nt * 16 + (lane & 15);
#pragma unroll
        for (int j = 0; j < 4; j++) {
          float v = acc[mt][nt][j];
          float u = 0.7978845608028654f * (v + 0.044715f * v * v * v);
          float g = 0.5f * v * (1.f + tanhf(u));
          hout[(size_t)(rbase + j) * N + col] = f2bf(g);
        }
      }
    }
  } else {
    float* out = (float*)OutP;
#pragma unroll
    for (int mt = 0; mt < 4; mt++) {
      int rbase = row0 + wm + mt * 16 + (lane >> 4) * 4;
      int sj[4]; float wj[4];
#pragma unroll
      for (int j = 0; j < 4; j++) {
        int s = toks[e * CCAP + rbase + j];
        sj[j] = s;
        wj[j] = (s >= 0) ? gatew[s] : 0.f;
      }
#pragma unroll
      for (int nt = 0; nt < 4; nt++) {
        int col = n0 + wn + nt * 16 + (lane & 15);
#pragma unroll
        for (int j = 0; j < 4; j++)
          if (sj[j] >= 0) out[(size_t)sj[j] * MDIM + col] = acc[mt][nt][j] * wj[j];
      }
    }
  }
}

extern "C" void kernel_launch(void* const* d_in, const int* in_sizes, int n_in,
                              void* d_out, int out_size, void* d_ws, size_t ws_size,
                              hipStream_t stream) {
  const float* x  = (const float*)d_in[0];
  const float* Wg = (const float*)d_in[1];
  const float* W1 = (const float*)d_in[2];
  const float* W2 = (const float*)d_in[3];

  char* p = (char*)d_ws;
  u16* W1t = (u16*)p;  p += (size_t)NEXP * HDIM * MDIM * 2;  // 268 MB  [E][H][M]
  u16* W2t = (u16*)p;  p += (size_t)NEXP * MDIM * HDIM * 2;  // 268 MB  [E][M][H]
  u16* xd  = (u16*)p;  p += (size_t)NEXP * CCAP * MDIM * 2;  //  67 MB  [E][C][M]
  u16* hb  = (u16*)p;  p += (size_t)NEXP * CCAP * HDIM * 2;  // 268 MB  [E][C][H]
  int*   eidx  = (int*)p;   p += S_TOK * 4;
  int*   slot  = (int*)p;   p += S_TOK * 4;
  float* gatew = (float*)p; p += S_TOK * 4;
  int*   toks  = (int*)p;   p += NEXP * CCAP * 4;
  int*   counts= (int*)p;   p += 256;

  (void)hipMemsetAsync(d_out, 0, (size_t)out_size * 4, stream);      // dropped tokens -> 0
  (void)hipMemsetAsync(toks, 0xFF, NEXP * CCAP * 4, stream);         // -1 = unfilled slot

  gate_kernel<<<S_TOK / 4, 256, 0, stream>>>(x, Wg, eidx, gatew);
  scan_kernel<<<1, 256, 0, stream>>>(eidx, gatew, slot, toks, counts);
  scatter_kernel<<<S_TOK, 256, 0, stream>>>(x, eidx, slot, xd);
  transpose_convert<<<dim3(HDIM / 32, MDIM / 32, NEXP), dim3(32, 8), 0, stream>>>(W1, W1t, MDIM, HDIM);
  transpose_convert<<<dim3(MDIM / 32, HDIM / 32, NEXP), dim3(32, 8), 0, stream>>>(W2, W2t, HDIM, MDIM);
  moe_gemm<MDIM, 0><<<dim3(HDIM / 128, CCAP / 128, NEXP), 256, 0, stream>>>(
      xd, W1t, hb, counts, nullptr, nullptr, HDIM);
  moe_gemm<HDIM, 1><<<dim3(MDIM / 128, CCAP / 128, NEXP), 256, 0, stream>>>(
      hb, W2t, d_out, counts, toks, gatew, MDIM);
}